// Round 5
// baseline (1525.685 us; speedup 1.0000x reference)
//
#include <hip/hip_runtime.h>

// Morphological skeleton, 16 x 1024 x 1024 f32.
// skel = sum_{k=0..20} ( e_k - dilate3x3(e_{k+1}) ),  e_0 = x, e_{k+1} = erode3x3(e_k)
// (reduce_window SAME semantics: windows clamp at image borders).
//
// Round-5: register-resident vertical pipeline, TWO ROWS PER STEP.
// 3 dispatches x G=7 fused stages. One wave (64 lanes x float4 = 256 cols)
// sweeps a 32-row chunk in 24 two-row steps (8 warm-up rows). Per stage:
// 2 carried rows (OB,MB) + 2 incoming; erode produces 2 rows (8 vmin3 +
// 4 independent shfl + 8 min3); dilate reuses stage s+1's carried rows
// (read before update) producing 2 term rows into an 8-slot FIFO with
// compile-time 4-phase rotation (no shift movs). Interior row-chunks take a
// mask-free template path (VEDGE=false); only chunks 0 and 31 pay the
// vertical border cndmasks.
//
// Correctness invariants (carried over from the round-4 verified kernel):
//  - OOB input rows enter as +BIG (erode identity == border clamp); synthetic
//    warm-up values are >= true erosion (cone argument) and the 8-row/8-col
//    halos exactly cover the contaminated region.
//  - dilate windows mask OOB rows to -BIG (VEDGE chunks only); garbage terms
//    land only in FIFO slots for rows outside [y0,y0+RCH), never emitted.
//  - bands {0,240,480,720,768} x 256 cols, disjoint write ownership
//    {[0,248),[248,488),[488,728),[728,968),[968,1024)}: the skel RMW never
//    races (halo lanes may read a racing skel cell but never store it).
//  - skpf/pf double-buffers: slot written at step k is consumed at step k+1
//    (distinct slots by parity), no clobber-before-use.

static constexpr int W = 1024, H = 1024, NIMG = 16;
static constexpr int RCH = 32;                 // output rows per wave
static constexpr int NSTEPS = (RCH + 16) / 2;  // 24 two-row steps
static constexpr float BIG = 3.0e38f;

__device__ __forceinline__ float min3f(float a, float b, float c) { return fminf(fminf(a, b), c); }
__device__ __forceinline__ float max3f(float a, float b, float c) { return fmaxf(fmaxf(a, b), c); }
__device__ __forceinline__ float4 vmin3(const float4& a, const float4& b, const float4& c) {
    float4 r; r.x = min3f(a.x,b.x,c.x); r.y = min3f(a.y,b.y,c.y);
    r.z = min3f(a.z,b.z,c.z); r.w = min3f(a.w,b.w,c.w); return r;
}
__device__ __forceinline__ float4 vmax3(const float4& a, const float4& b, const float4& c) {
    float4 r; r.x = max3f(a.x,b.x,c.x); r.y = max3f(a.y,b.y,c.y);
    r.z = max3f(a.z,b.z,c.z); r.w = max3f(a.w,b.w,c.w); return r;
}
__device__ __forceinline__ float4 hmin(const float4& v, float l, float r) {
    float4 e; e.x = min3f(l, v.x, v.y); e.y = min3f(v.x, v.y, v.z);
    e.z = min3f(v.y, v.z, v.w); e.w = min3f(v.z, v.w, r); return e;
}
__device__ __forceinline__ float4 hmax(const float4& v, float l, float r) {
    float4 e; e.x = max3f(l, v.x, v.y); e.y = max3f(v.x, v.y, v.z);
    e.z = max3f(v.y, v.z, v.w); e.w = max3f(v.z, v.w, r); return e;
}

struct PipeState {
    float4 OB[7], MB[7];   // stage s carried rows f_s(q-2), f_s(q-1), q = t-s
    float4 OD, MD;         // f_7(t-9), f_7(t-8)
    float4 acc[8];         // term FIFO, logical i -> phys (i + 2*step) & 7
    float4 pf[4];          // input double-buffer (2 rows x 2 parities)
    float4 skpf[4];        // old-skel double-buffer
};

template<bool FIRST, bool WRITE_E, bool VEDGE, int R>
__device__ __forceinline__
void step2(PipeState& S, int t, int y0, int lane, int gx,
           bool lE, bool rE, bool lane_ok,
           const float* __restrict__ in, float* __restrict__ eo,
           float* __restrict__ sk)
{
    constexpr int P = (R & 1) * 2;       // consume slots P, P+1
    constexpr int Q = 2 - (R & 1) * 2;   // load slots Q, Q+1 (next step's P)
    const float4 big4  = make_float4(BIG, BIG, BIG, BIG);
    const float4 mbig4 = make_float4(-BIG, -BIG, -BIG, -BIG);

    // consume input rows t, t+1 (OOB rows -> +BIG, VEDGE chunks only)
    float4 c0, c1;
    if (VEDGE) {
        c0 = ((unsigned)t       < (unsigned)H) ? S.pf[P]     : big4;
        c1 = ((unsigned)(t + 1) < (unsigned)H) ? S.pf[P + 1] : big4;
    } else { c0 = S.pf[P]; c1 = S.pf[P + 1]; }

    // prefetch rows t+2, t+3 for the next step
    if (t + 2 <= y0 + RCH + 7) {
        if (!VEDGE || (unsigned)(t + 2) < (unsigned)H)
            S.pf[Q] = *(const float4*)&in[(size_t)(t + 2) * W + gx];
        else S.pf[Q] = big4;
        if (!VEDGE || (unsigned)(t + 3) < (unsigned)H)
            S.pf[Q + 1] = *(const float4*)&in[(size_t)(t + 3) * W + gx];
        else S.pf[Q + 1] = big4;
    }

#pragma unroll
    for (int s = 0; s < 7; ++s) {
        // entry: OB[s]=f_s(q-2), MB[s]=f_s(q-1), c0=f_s(q), c1=f_s(q+1), q=t-s
        const float4 fO = S.OB[s], fM = S.MB[s];

        // ---- erode: en0 = f_{s+1}(q-1), en1 = f_{s+1}(q) ----
        float4 vm0 = vmin3(fO, fM, c0);
        float4 vm1 = vmin3(fM, c0, c1);
        float l0 = __shfl(vm0.w, lane - 1), r0 = __shfl(vm0.x, lane + 1);
        float l1 = __shfl(vm1.w, lane - 1), r1 = __shfl(vm1.x, lane + 1);
        if (lE) { l0 = BIG; l1 = BIG; }
        if (rE) { r0 = BIG; r1 = BIG; }
        float4 en0 = hmin(vm0, l0, r0);
        float4 en1 = hmin(vm1, l1, r1);
        S.OB[s] = c0; S.MB[s] = c1;

        // ---- dilate of f_{s+1} at rows q-2 (d0) and q-1 (d1) ----
        // stage s+1 buffers read BEFORE their update (iteration s+1):
        // OB[s+1] = f_{s+1}(q-3), MB[s+1] = f_{s+1}(q-2)
        float4 gO = (s < 6) ? S.OB[s + 1] : S.OD;
        float4 gM = (s < 6) ? S.MB[s + 1] : S.MD;
        float4 a0 = gO, b0 = en0, a1 = gM, b1 = en1;
        if (VEDGE) {                       // OOB rows must lose the max
            if (t - s - 3 < 0)  a0 = mbig4;
            if (t - s - 1 >= H) b0 = mbig4;
            if (t - s - 2 < 0)  a1 = mbig4;
            if (t - s     >= H) b1 = mbig4;
        }
        float4 vx0 = vmax3(a0, gM,  b0);
        float4 vx1 = vmax3(a1, en0, b1);
        float dl0 = __shfl(vx0.w, lane - 1), dr0 = __shfl(vx0.x, lane + 1);
        float dl1 = __shfl(vx1.w, lane - 1), dr1 = __shfl(vx1.x, lane + 1);
        if (lE) { dl0 = -BIG; dl1 = -BIG; }
        if (rE) { dr0 = -BIG; dr1 = -BIG; }
        float4 dn0 = hmax(vx0, dl0, dr0);
        float4 dn1 = hmax(vx1, dl1, dr1);

        // term rows q-2 -> logical slot 6-s, q-1 -> 7-s
        float4& A0 = S.acc[((6 - s) + 2 * R) & 7];
        float4& A1 = S.acc[((7 - s) + 2 * R) & 7];
        A0.x += fO.x - dn0.x; A0.y += fO.y - dn0.y;
        A0.z += fO.z - dn0.z; A0.w += fO.w - dn0.w;
        A1.x += fM.x - dn1.x; A1.y += fM.y - dn1.y;
        A1.z += fM.z - dn1.z; A1.w += fM.w - dn1.w;

        if (s == 6) {
            S.OD = en0; S.MD = en1;        // f_7(t-7), f_7(t-6)
            if (WRITE_E) {
                if (t - 7 >= y0 && t - 7 < y0 + RCH && lane_ok)
                    *(float4*)&eo[(size_t)(t - 7) * W + gx] = en0;
                if (t - 6 >= y0 && t - 6 < y0 + RCH && lane_ok)
                    *(float4*)&eo[(size_t)(t - 6) * W + gx] = en1;
            }
        }
        c0 = en0; c1 = en1;
    }

    // ---- emit completed rows t-8 (logical 0), t-7 (logical 1) ----
    if (t >= y0 + 8) {
        float4 v0 = S.acc[(0 + 2 * R) & 7];
        float4 v1 = S.acc[(1 + 2 * R) & 7];
        if (!FIRST) {
            const float4 o0 = S.skpf[P], o1 = S.skpf[P + 1];
            v0.x += o0.x; v0.y += o0.y; v0.z += o0.z; v0.w += o0.w;
            v1.x += o1.x; v1.y += o1.y; v1.z += o1.z; v1.w += o1.w;
        }
        if (lane_ok) {
            *(float4*)&sk[(size_t)(t - 8) * W + gx] = v0;
            *(float4*)&sk[(size_t)(t - 7) * W + gx] = v1;
        }
    }
    S.acc[(0 + 2 * R) & 7] = make_float4(0.f, 0.f, 0.f, 0.f);
    S.acc[(1 + 2 * R) & 7] = make_float4(0.f, 0.f, 0.f, 0.f);

    // prefetch old skel rows t-6, t-5 (emitted next step; read-before-write
    // within this wave, disjoint ownership across waves)
    if (!FIRST) {
        if (t - 6 >= y0 && t - 6 < y0 + RCH) {
            S.skpf[Q]     = *(const float4*)&sk[(size_t)(t - 6) * W + gx];
            S.skpf[Q + 1] = *(const float4*)&sk[(size_t)(t - 5) * W + gx];
        }
    }
}

template<bool FIRST, bool WRITE_E, bool VEDGE>
__device__ __forceinline__
void sweep(int y0, int lane, int gx, bool lE, bool rE, bool lane_ok,
           const float* __restrict__ in, float* __restrict__ eo,
           float* __restrict__ sk)
{
    PipeState S;
    const float4 big4 = make_float4(BIG, BIG, BIG, BIG);
    const float4 z4   = make_float4(0.f, 0.f, 0.f, 0.f);
#pragma unroll
    for (int s = 0; s < 7; ++s) { S.OB[s] = big4; S.MB[s] = big4; }
    S.OD = big4; S.MD = big4;
#pragma unroll
    for (int i = 0; i < 8; ++i) S.acc[i] = z4;
#pragma unroll
    for (int i = 0; i < 4; ++i) { S.pf[i] = big4; S.skpf[i] = z4; }

    int t = y0 - 8;
    if (!VEDGE || (unsigned)t < (unsigned)H)
        S.pf[0] = *(const float4*)&in[(size_t)t * W + gx];
    if (!VEDGE || (unsigned)(t + 1) < (unsigned)H)
        S.pf[1] = *(const float4*)&in[(size_t)(t + 1) * W + gx];

#pragma unroll 1
    for (int it = 0; it < NSTEPS; it += 4) {
        step2<FIRST, WRITE_E, VEDGE, 0>(S, t,     y0, lane, gx, lE, rE, lane_ok, in, eo, sk);
        step2<FIRST, WRITE_E, VEDGE, 1>(S, t + 2, y0, lane, gx, lE, rE, lane_ok, in, eo, sk);
        step2<FIRST, WRITE_E, VEDGE, 2>(S, t + 4, y0, lane, gx, lE, rE, lane_ok, in, eo, sk);
        step2<FIRST, WRITE_E, VEDGE, 3>(S, t + 6, y0, lane, gx, lE, rE, lane_ok, in, eo, sk);
        t += 8;
    }
}

template<bool FIRST, bool WRITE_E>
__global__ __launch_bounds__(64, 2)
void skel_pipe2(const float* __restrict__ ein, float* __restrict__ eout,
                float* __restrict__ skel)
{
    const int lane = threadIdx.x;          // one wave per block
    const int bx = blockIdx.x;             // band 0..4
    const int y0 = blockIdx.y * RCH;       // row chunk
    const int img = blockIdx.z;
    const int x0 = (bx == 4) ? 768 : bx * 240;
    const int gx = x0 + 4 * lane;          // gx max = 768+252 = 1020

    const size_t base = (size_t)img * (size_t)(W * H);
    const float* __restrict__ in = ein + base;
    float* __restrict__ eo = eout + base;
    float* __restrict__ sk = skel + base;

    const bool lE = (gx == 0);
    const bool rE = (gx + 4 == W);
    const int own_lo = (bx == 0) ? 0 : ((bx == 4) ? 968 : x0 + 8);
    const int own_hi = (bx == 4) ? W : x0 + 248;
    const bool lane_ok = (gx >= own_lo) && (gx < own_hi);

    if (y0 == 0 || y0 + RCH == H)
        sweep<FIRST, WRITE_E, true >(y0, lane, gx, lE, rE, lane_ok, in, eo, sk);
    else
        sweep<FIRST, WRITE_E, false>(y0, lane, gx, lE, rE, lane_ok, in, eo, sk);
}

extern "C" void kernel_launch(void* const* d_in, const int* in_sizes, int n_in,
                              void* d_out, int out_size, void* d_ws, size_t ws_size,
                              hipStream_t stream)
{
    const float* x = (const float*)d_in[0];
    float* skel = (float*)d_out;
    const size_t n = (size_t)NIMG * W * H;

    float* e0 = (float*)d_ws;
    float* e1 = e0 + n;

    dim3 grid(5, H / RCH, NIMG);
    dim3 block(64);

    // steps 0-6: x -> e0 ; 7-13: e0 -> e1 ; 14-20: e1 -> (none)
    skel_pipe2<true,  true ><<<grid, block, 0, stream>>>(x,  e0, skel);
    skel_pipe2<false, true ><<<grid, block, 0, stream>>>(e0, e1, skel);
    skel_pipe2<false, false><<<grid, block, 0, stream>>>(e1, e0, skel);
}